// Round 6
// baseline (1249.037 us; speedup 1.0000x reference)
//
#include <hip/hip_runtime.h>
#include <math.h>

// Shapes
#define BB  512
#define SS  23
#define DD  768
#define EE  8
#define NHH 8
#define RR  256
#define HDD 32
#define LL  50
#define HH2 384            // D/2
#define TT  (BB*SS)        // 11776
#define LN_EPS 1e-5f
#define TBE 8              // tokens per expert-pair block
#define MAXWORK 1536       // >= TT/TBE + 56 (max compacted chunks)

__device__ __forceinline__ float block_sum(float v, float* red, int nw){
  #pragma unroll
  for (int o = 32; o > 0; o >>= 1) v += __shfl_down(v, o, 64);
  int wid = threadIdx.x >> 6;
  __syncthreads();
  if ((threadIdx.x & 63) == 0) red[wid] = v;
  __syncthreads();
  float s = 0.f;
  for (int i = 0; i < nw; ++i) s += red[i];
  return s;
}

__device__ __forceinline__ float gelu(float v){
  return 0.5f*v*(1.f + erff(v*0.70710678118654752f));
}

// ---------------- K1: masked-mean context [B,D] ----------------
__global__ void k_context(const float* __restrict__ emb, const int* __restrict__ existing,
                          float* __restrict__ ctx){
  int b = blockIdx.x, tid = threadIdx.x;
  float acc0=0.f, acc1=0.f, acc2=0.f;
  int cnt = 0;
  for (int s = 0; s < SS; ++s){
    if (existing[b*SS + s]){
      ++cnt;
      const float* row = emb + ((size_t)(b*SS + s))*DD;
      acc0 += row[tid]; acc1 += row[tid+256]; acc2 += row[tid+512];
    }
  }
  float inv = 1.0f / ((float)cnt + 1e-8f);
  ctx[(size_t)b*DD + tid      ] = acc0*inv;
  ctx[(size_t)b*DD + tid + 256] = acc1*inv;
  ctx[(size_t)b*DD + tid + 512] = acc2*inv;
}

// ---------------- K2: DPE -> pos [S,E,D] ----------------
__global__ void k_pos(const float* __restrict__ mt,
                      const float* __restrict__ w0, const float* __restrict__ bi0,
                      const float* __restrict__ w1, const float* __restrict__ bi1,
                      const float* __restrict__ w2, const float* __restrict__ bi2,
                      const float* __restrict__ wo, const float* __restrict__ bo,
                      const float* __restrict__ lng, const float* __restrict__ lnb,
                      float* __restrict__ pos){
  int s = blockIdx.x / EE, e = blockIdx.x % EE, tid = threadIdx.x;
  __shared__ float def[DD];
  __shared__ float hA[RR], hB[RR];
  __shared__ float red[8];
  for (int j = tid; j < DD; j += 256) def[j] = mt[s*DD + j];
  __syncthreads();
  float acc = 0.f;
  { const float* W = w0 + (size_t)e*DD*RR;
    for (int d = 0; d < DD; ++d) acc += def[d] * W[(size_t)d*RR + tid]; }
  hA[tid] = fmaxf(acc + bi0[e*RR + tid], 0.f);
  __syncthreads();
  acc = 0.f;
  { const float* W = w1 + (size_t)e*RR*RR;
    for (int kk = 0; kk < RR; ++kk) acc += hA[kk] * W[kk*RR + tid]; }
  hB[tid] = fmaxf(acc + bi1[e*RR + tid], 0.f);
  __syncthreads();
  acc = 0.f;
  { const float* W = w2 + (size_t)e*RR*RR;
    for (int kk = 0; kk < RR; ++kk) acc += hB[kk] * W[kk*RR + tid]; }
  __syncthreads();
  hA[tid] = fmaxf(acc + bi2[e*RR + tid], 0.f);
  __syncthreads();
  float o[3];
  const float* Wo = wo + (size_t)e*RR*DD;
  #pragma unroll
  for (int j = 0; j < 3; ++j){
    int d = tid + j*256;
    float a = 0.f;
    for (int kk = 0; kk < RR; ++kk) a += hA[kk] * Wo[(size_t)kk*DD + d];
    o[j] = a + bo[e*DD + d] + def[d];
  }
  float mean = block_sum(o[0]+o[1]+o[2], red, 4) * (1.f/DD);
  float dv = 0.f;
  #pragma unroll
  for (int j = 0; j < 3; ++j){ float c = o[j]-mean; dv += c*c; }
  float rstd = rsqrtf(block_sum(dv, red, 4) * (1.f/DD) + LN_EPS);
  #pragma unroll
  for (int j = 0; j < 3; ++j){
    int d = tid + j*256;
    pos[((size_t)(s*EE + e))*DD + d] =
      (o[j]-mean)*rstd*lng[e*DD + d] + lnb[e*DD + d];
  }
}

// ---------------- K2b: posF/posG [S,E,R] ----------------
__global__ void k_posFG(const float* __restrict__ pos,
                        const float* __restrict__ fw1p, const float* __restrict__ gw1p,
                        float* __restrict__ posF, float* __restrict__ posG){
  int s = blockIdx.x / EE, e = blockIdx.x % EE, tid = threadIdx.x;
  __shared__ float p[DD];
  for (int j = tid; j < DD; j += 256) p[j] = pos[((size_t)(s*EE + e))*DD + j];
  __syncthreads();
  float aF = 0.f, aG = 0.f;
  const float* WF = fw1p + (size_t)e*DD*RR;
  const float* WG = gw1p + (size_t)e*DD*RR;
  for (int d = 0; d < DD; ++d){
    float pv = p[d];
    aF += pv * WF[(size_t)d*RR + tid];
    aG += pv * WG[(size_t)d*RR + tid];
  }
  posF[(s*EE + e)*RR + tid] = aF;
  posG[(s*EE + e)*RR + tid] = aG;
}

// ---------------- K2c: router default half [S,R] ----------------
__global__ void k_rtrD(const float* __restrict__ mt, const float* __restrict__ rw1,
                       float* __restrict__ rtrD){
  int s = blockIdx.x, tid = threadIdx.x;
  __shared__ float def[DD];
  for (int j = tid; j < DD; j += 256) def[j] = mt[s*DD + j];
  __syncthreads();
  float a = 0.f;
  for (int d = 0; d < DD; ++d) a += def[d] * rw1[(size_t)d*RR + tid];
  rtrD[s*RR + tid] = a;
}

// ---------------- K3: ctxF/ctxG [B,E,R], 16 rows/block, 512 threads ----------------
__global__ __launch_bounds__(512) void k_ctxFG(const float* __restrict__ ctx,
                        const float* __restrict__ fw1c, const float* __restrict__ gw1c,
                        float* __restrict__ ctxF, float* __restrict__ ctxG){
  int grp = blockIdx.x >> 3;
  int e   = blockIdx.x & 7;
  int b0  = grp*16;
  int tid = threadIdx.x;
  int ty = tid >> 6;              // wave 0..7 -> rows ty*2..+1
  int tx = tid & 63;              // cols tx*4..+3
  __shared__ float c[16*DD];      // 48KB
  {
    const float4* src = (const float4*)(ctx + (size_t)b0*DD);
    float4* dst = (float4*)c;
    for (int i = tid; i < 16*DD/4; i += 512) dst[i] = src[i];
  }
  __syncthreads();
  float aF[2][4] = {}, aG[2][4] = {};
  const float* WF = fw1c + (size_t)e*DD*RR + tx*4;
  const float* WG = gw1c + (size_t)e*DD*RR + tx*4;
  #pragma unroll 4
  for (int d = 0; d < DD; ++d){
    float4 wf = *(const float4*)(WF + (size_t)d*RR);
    float4 wg = *(const float4*)(WG + (size_t)d*RR);
    #pragma unroll
    for (int i = 0; i < 2; ++i){
      float cv = c[(ty*2+i)*DD + d];
      aF[i][0] += cv*wf.x; aF[i][1] += cv*wf.y; aF[i][2] += cv*wf.z; aF[i][3] += cv*wf.w;
      aG[i][0] += cv*wg.x; aG[i][1] += cv*wg.y; aG[i][2] += cv*wg.z; aG[i][3] += cv*wg.w;
    }
  }
  #pragma unroll
  for (int i = 0; i < 2; ++i){
    size_t o = ((size_t)(b0 + ty*2 + i)*EE + e)*RR + tx*4;
    *(float4*)(ctxF + o) = make_float4(aF[i][0],aF[i][1],aF[i][2],aF[i][3]);
    *(float4*)(ctxG + o) = make_float4(aG[i][0],aG[i][1],aG[i][2],aG[i][3]);
  }
}

// ---------------- K3b: router ctx half [B,R], 4 rows/block ----------------
__global__ __launch_bounds__(256) void k_rtrC(const float* __restrict__ ctx, const float* __restrict__ rw1,
                       float* __restrict__ rtrC){
  int b0 = blockIdx.x*4, tid = threadIdx.x;
  int ty = tid >> 6, tx = tid & 63;
  __shared__ float c[4*DD];            // 12KB
  {
    const float4* src = (const float4*)(ctx + (size_t)b0*DD);
    float4* dst = (float4*)c;
    for (int i = tid; i < 4*DD/4; i += 256) dst[i] = src[i];
  }
  __syncthreads();
  float a[4] = {};
  const float* W = rw1 + (size_t)DD*RR + tx*4;
  #pragma unroll 4
  for (int d = 0; d < DD; ++d){
    float4 w = *(const float4*)(W + (size_t)d*RR);
    float cv = c[ty*DD + d];
    a[0] += cv*w.x; a[1] += cv*w.y; a[2] += cv*w.z; a[3] += cv*w.w;
  }
  *(float4*)(rtrC + (size_t)(b0+ty)*RR + tx*4) = make_float4(a[0],a[1],a[2],a[3]);
}

// ---------------- K4: router (wave/token) -> pair buckets; copies existing rows ----------------
__global__ void k_router(const float* __restrict__ emb, const int* __restrict__ existing,
                         const float* __restrict__ rtrD, const float* __restrict__ rtrC,
                         const float* __restrict__ rb1, const float* __restrict__ rw2,
                         const float* __restrict__ rb2,
                         int* __restrict__ cnt, int* __restrict__ listT,
                         float* __restrict__ listW, float* __restrict__ sec){
  int wv = threadIdx.x >> 6, lane = threadIdx.x & 63;
  int t = blockIdx.x*4 + wv;
  int b = t / SS, s = t - b*SS;
  if (existing[t]){
    #pragma unroll
    for (int j = 0; j < DD/64; ++j)
      sec[(size_t)t*DD + lane + j*64] = emb[(size_t)t*DD + lane + j*64];
    return;
  }
  float acc[EE] = {};
  #pragma unroll
  for (int j = 0; j < 4; ++j){
    int idx = lane + j*64;
    float hr = fmaxf(rtrD[s*RR + idx] + rtrC[(size_t)b*RR + idx] + rb1[idx], 0.f);
    #pragma unroll
    for (int e = 0; e < EE; ++e) acc[e] += hr * rw2[idx*EE + e];
  }
  #pragma unroll
  for (int e = 0; e < EE; ++e)
    #pragma unroll
    for (int o = 32; o > 0; o >>= 1) acc[e] += __shfl_xor(acc[e], o, 64);
  if (lane == 0){
    float sc[EE];
    float m = -1e30f;
    #pragma unroll
    for (int e = 0; e < EE; ++e){ sc[e] = acc[e] + rb2[e]; m = fmaxf(m, sc[e]); }
    float w[EE]; float Z = 0.f;
    #pragma unroll
    for (int e = 0; e < EE; ++e){ w[e] = expf(sc[e]-m); Z += w[e]; }
    int i0 = 0;
    for (int e = 1; e < EE; ++e) if (w[e] > w[i0]) i0 = e;
    int i1 = -1;
    for (int e = 0; e < EE; ++e) if (e != i0 && (i1 < 0 || w[e] > w[i1])) i1 = e;
    float iz = 1.f/Z;
    int p = i0*EE + i1;
    int idx = atomicAdd(&cnt[p], 1);
    size_t g = (size_t)p*TT + idx;
    listT[g] = t;
    listW[g*2]   = w[i0]*iz;
    listW[g*2+1] = w[i1]*iz;
  }
}

// ---------------- K4b: compact (pair,chunk) work list ----------------
__global__ void k_sched(const int* __restrict__ cnt, int* __restrict__ work,
                        int* __restrict__ wtotal){
  int tid = threadIdx.x;          // 64 threads
  __shared__ int chs[64];
  __shared__ int base[64];
  int n = cnt[tid];
  chs[tid] = (n + TBE - 1) / TBE;
  __syncthreads();
  if (tid == 0){
    int acc = 0;
    for (int p = 0; p < 64; ++p){ base[p] = acc; acc += chs[p]; }
    wtotal[0] = acc;
  }
  __syncthreads();
  int b0 = base[tid], ch = chs[tid];
  for (int j = 0; j < ch; ++j) work[b0 + j] = (tid << 16) | j;
}

// ---------------- K5: expert-pair eval, 8 tokens/block -> sec (missing rows) ----------------
__global__ __launch_bounds__(256) void k_expert(
    const float* __restrict__ ctx,
    const float* __restrict__ ctxF, const float* __restrict__ ctxG,
    const float* __restrict__ posF, const float* __restrict__ posG,
    const float* __restrict__ fb1, const float* __restrict__ fw2, const float* __restrict__ fb2,
    const float* __restrict__ gb1, const float* __restrict__ gw2, const float* __restrict__ gb2,
    const float* __restrict__ elng, const float* __restrict__ elnb,
    const int* __restrict__ cnt, const int* __restrict__ listT, const float* __restrict__ listW,
    const int* __restrict__ work, const int* __restrict__ wtotal,
    float* __restrict__ sec){
  int wi = blockIdx.x;
  if (wi >= wtotal[0]) return;
  int ent = work[wi];
  int p = ent >> 16, chunk = ent & 0xffff;
  int n = cnt[p];
  int e0 = p >> 3, e1 = p & 7;
  int nt = n - chunk*TBE; if (nt > TBE) nt = TBE;
  int tid = threadIdx.x;
  __shared__ float hfs[TBE*RR];     // 8KB
  __shared__ float mixbuf[TBE*DD];  // 24KB
  __shared__ float gates[TBE];
  __shared__ int   tks[TBE], tkb[TBE], tkss[TBE];
  __shared__ float sws[TBE][2];
  if (tid < TBE){
    int ok = tid < nt;
    size_t g = (size_t)p*TT + chunk*TBE + (ok ? tid : 0);
    int t = listT[g];
    tks[tid] = t; tkb[tid] = t/SS; tkss[tid] = t - (t/SS)*SS;
    sws[tid][0] = listW[g*2]; sws[tid][1] = listW[g*2+1];
  }
  __syncthreads();
  float outreg[2][DD/64] = {};
  int wv = tid >> 6, lane = tid & 63;
  int ty = tid >> 7, tx = tid & 127;
  for (int xp = 0; xp < 2; ++xp){
    int e = xp ? e1 : e0;
    for (int idx2 = tid; idx2 < TBE*RR; idx2 += 256){
      int i = idx2 >> 8, kk = idx2 & 255;
      float v = 0.f;
      if (i < nt){
        int b = tkb[i], s = tkss[i];
        v = fmaxf(ctxF[((size_t)b*EE+e)*RR + kk] + posF[(s*EE+e)*RR + kk] + fb1[e*RR + kk], 0.f);
      }
      hfs[idx2] = v;
    }
    #pragma unroll
    for (int ii = 0; ii < 2; ++ii){
      int it = wv*2 + ii;
      if (it < nt){
        int b = tkb[it], s = tkss[it];
        float g = 0.f;
        #pragma unroll
        for (int j = 0; j < 4; ++j){
          int idx = lane + j*64;
          float hg = fmaxf(ctxG[((size_t)b*EE+e)*RR + idx] + posG[(s*EE+e)*RR + idx]
                           + gb1[e*RR + idx], 0.f);
          g += hg * gw2[e*RR + idx];
        }
        #pragma unroll
        for (int o = 32; o > 0; o >>= 1) g += __shfl_xor(g, o, 64);
        if (lane == 0) gates[it] = 1.f/(1.f + expf(-(g + gb2[e])));
      }
    }
    __syncthreads();
    float acc[4][6] = {};
    const float* W = fw2 + (size_t)e*RR*DD + tx*6;
    #pragma unroll 4
    for (int kk = 0; kk < RR; ++kk){
      const float* wr = W + (size_t)kk*DD;
      float w0=wr[0], w1v=wr[1], w2v=wr[2], w3=wr[3], w4=wr[4], w5=wr[5];
      #pragma unroll
      for (int i = 0; i < 4; ++i){
        float h = hfs[(ty*4+i)*RR + kk];
        acc[i][0]+=h*w0; acc[i][1]+=h*w1v; acc[i][2]+=h*w2v;
        acc[i][3]+=h*w3; acc[i][4]+=h*w4;  acc[i][5]+=h*w5;
      }
    }
    #pragma unroll
    for (int i = 0; i < 4; ++i){
      int it = ty*4 + i;
      if (it < nt){
        float g = gates[it]; int b = tkb[it];
        #pragma unroll
        for (int j = 0; j < 6; ++j){
          int d = tx*6 + j;
          float cand = acc[i][j] + fb2[e*DD + d];
          mixbuf[it*DD + d] = g*cand + (1.f-g)*ctx[(size_t)b*DD + d];
        }
      }
    }
    __syncthreads();
    #pragma unroll
    for (int ii = 0; ii < 2; ++ii){
      int it = wv*2 + ii;
      if (it < nt){
        float sum = 0.f, sq = 0.f;
        #pragma unroll
        for (int j = 0; j < DD/64; ++j){
          float v2 = mixbuf[it*DD + lane + j*64];
          sum += v2; sq += v2*v2;
        }
        #pragma unroll
        for (int o = 32; o > 0; o >>= 1){
          sum += __shfl_xor(sum, o, 64); sq += __shfl_xor(sq, o, 64);
        }
        float mean = sum*(1.f/DD);
        float rstd = rsqrtf(sq*(1.f/DD) - mean*mean + LN_EPS);
        float sw = sws[it][xp];
        #pragma unroll
        for (int j = 0; j < DD/64; ++j){
          int d = lane + j*64;
          float v2 = (mixbuf[it*DD + d]-mean)*rstd*elng[e*DD + d] + elnb[e*DD + d];
          outreg[ii][j] += sw*v2;
        }
      }
    }
    __syncthreads();
  }
  for (int ii = 0; ii < 2; ++ii){
    int it = wv*2 + ii;
    if (it < nt){
      int t = tks[it];
      #pragma unroll
      for (int j = 0; j < DD/64; ++j)
        sec[(size_t)t*DD + lane + j*64] = outreg[ii][j];
    }
  }
}

// ---------------- K6: x1 = gelu(sec @ red_w1 + b1), 24 tokens/block ----------------
__global__ __launch_bounds__(384) void k_red1(const float* __restrict__ sec, const float* __restrict__ w1,
                       const float* __restrict__ b1v, float* __restrict__ x1){
  int t0 = blockIdx.x * 24, tid = threadIdx.x;   // 384 threads
  int ty = tid / 96, tx = tid % 96;              // 4 grps x 6 tokens; 96 out-grps(4)
  int nt = TT - t0; if (nt > 24) nt = 24;
  __shared__ float sx[24*DD];                    // 72KB -> 2 blocks/CU
  for (int i = 0; i < 24; ++i){
    float4* dst = (float4*)(sx + i*DD);
    if (i < nt){
      const float4* src = (const float4*)(sec + (size_t)(t0+i)*DD);
      for (int j = tid; j < DD/4; j += 384) dst[j] = src[j];
    } else {
      for (int j = tid; j < DD/4; j += 384) dst[j] = make_float4(0.f,0.f,0.f,0.f);
    }
  }
  __syncthreads();
  float a[6][4] = {};
  const float* W = w1 + tx*4;
  #pragma unroll 4
  for (int d = 0; d < DD; ++d){
    float4 w = *(const float4*)(W + (size_t)d*HH2);
    #pragma unroll
    for (int i = 0; i < 6; ++i){
      float xv = sx[(ty*6+i)*DD + d];
      a[i][0]+=xv*w.x; a[i][1]+=xv*w.y; a[i][2]+=xv*w.z; a[i][3]+=xv*w.w;
    }
  }
  float4 bb = *(const float4*)(b1v + tx*4);
  #pragma unroll
  for (int i = 0; i < 6; ++i){
    int it = ty*6 + i;
    if (it < nt){
      float v0=gelu(a[i][0]+bb.x), v1=gelu(a[i][1]+bb.y);
      float v2=gelu(a[i][2]+bb.z), v3=gelu(a[i][3]+bb.w);
      *(float4*)(x1 + (size_t)(t0+it)*HH2 + tx*4) = make_float4(v0,v1,v2,v3);
    }
  }
}

// ---------------- K7a: xr = LN(gelu(x1 @ red_w2 + b2)), 32 tokens/block ----------------
__global__ __launch_bounds__(256) void k_red2(
    const float* __restrict__ x1, const float* __restrict__ w2, const float* __restrict__ b2v,
    const float* __restrict__ lng, const float* __restrict__ lnb,
    float* __restrict__ xr){
  int t0 = blockIdx.x * 32, tid = threadIdx.x;
  int ty = tid >> 6, tx = tid & 63;   // wave ty -> tokens ty*8..+7; cols tx*4..+3
  __shared__ float sx[32*HH2];        // 48KB
  {
    const float4* src = (const float4*)(x1 + (size_t)t0*HH2);
    float4* dst = (float4*)sx;
    for (int i = tid; i < 32*HH2/4; i += 256) dst[i] = src[i];
  }
  __syncthreads();
  float a[8][4] = {};
  const float* W = w2 + tx*4;
  #pragma unroll 4
  for (int d = 0; d < HH2; ++d){
    float4 w = *(const float4*)(W + (size_t)d*RR);
    #pragma unroll
    for (int i = 0; i < 8; ++i){
      float xv = sx[(ty*8+i)*HH2 + d];   // wave-uniform broadcast
      a[i][0]+=xv*w.x; a[i][1]+=xv*w.y; a[i][2]+=xv*w.z; a[i][3]+=xv*w.w;
    }
  }
  float4 bb = *(const float4*)(b2v + tx*4);
  float4 g4 = *(const float4*)(lng + tx*4);
  float4 be4 = *(const float4*)(lnb + tx*4);
  #pragma unroll
  for (int i = 0; i < 8; ++i){
    float v0=gelu(a[i][0]+bb.x), v1=gelu(a[i][1]+bb.y);
    float v2=gelu(a[i][2]+bb.z), v3=gelu(a[i][3]+bb.w);
    float sum = v0+v1+v2+v3;
    float sq  = v0*v0+v1*v1+v2*v2+v3*v3;
    #pragma unroll
    for (int o = 32; o > 0; o >>= 1){ sum += __shfl_xor(sum,o,64); sq += __shfl_xor(sq,o,64); }
    float mean = sum*(1.f/RR);
    float rstd = rsqrtf(sq*(1.f/RR) - mean*mean + LN_EPS);
    float o0 = (v0-mean)*rstd*g4.x + be4.x;
    float o1 = (v1-mean)*rstd*g4.y + be4.y;
    float o2 = (v2-mean)*rstd*g4.z + be4.z;
    float o3 = (v3-mean)*rstd*g4.w + be4.w;
    *(float4*)(xr + (size_t)(t0+ty*8+i)*RR + tx*4) = make_float4(o0,o1,o2,o3);
  }
}

// ---------------- K7b: q/k/v = xr @ qkv_w[m] + b, grid (TT/32, 3), 32 tok/block ----------------
__global__ __launch_bounds__(256) void k_qkv(
    const float* __restrict__ xr, const float* __restrict__ qkvw, const float* __restrict__ qkvb,
    float* __restrict__ q, float* __restrict__ k, float* __restrict__ v){
  int t0 = blockIdx.x * 32, m = blockIdx.y, tid = threadIdx.x;
  int ty = tid >> 6, tx = tid & 63;   // wave -> 8 tokens; cols tx*4
  __shared__ float sx[32*RR];        // 32KB
  {
    const float4* src = (const float4*)(xr + (size_t)t0*RR);
    float4* dst = (float4*)sx;
    for (int i = tid; i < 32*RR/4; i += 256) dst[i] = src[i];
  }
  __syncthreads();
  float a[8][4] = {};
  const float* W = qkvw + (size_t)m*RR*RR + tx*4;
  #pragma unroll 8
  for (int d = 0; d < RR; ++d){
    float4 w = *(const float4*)(W + (size_t)d*RR);
    #pragma unroll
    for (int i = 0; i < 8; ++i){
      float xv = sx[(ty*8+i)*RR + d];
      a[i][0]+=xv*w.x; a[i][1]+=xv*w.y; a[i][2]+=xv*w.z; a[i][3]+=xv*w.w;
    }
  }
  float4 bb = *(const float4*)(qkvb + m*RR + tx*4);
  float* outp = (m == 0) ? q : (m == 1) ? k : v;
  #pragma unroll
  for (int i = 0; i < 8; ++i){
    *(float4*)(outp + (size_t)(t0+ty*8+i)*RR + tx*4) =
      make_float4(a[i][0]+bb.x, a[i][1]+bb.y, a[i][2]+bb.z, a[i][3]+bb.w);
  }
}

// ---------------- K9: attention per (b,head) ----------------
__global__ void k_attn(const float* __restrict__ q, const float* __restrict__ k,
                       const float* __restrict__ v, float* __restrict__ o){
  int bh = blockIdx.x, b = bh / NHH, h = bh % NHH, tid = threadIdx.x;
  __shared__ float qs[SS][HDD], ks[SS][HDD], vs[SS][HDD];
  __shared__ float scr[SS][SS+1];
  for (int idx = tid; idx < SS*HDD; idx += 256){
    int s = idx / HDD, d = idx % HDD;
    size_t g = ((size_t)(b*SS + s))*RR + h*HDD + d;
    qs[s][d] = q[g]; ks[s][d] = k[g]; vs[s][d] = v[g];
  }
  __syncthreads();
  const float scale = 0.17677669529663687f;  // 1/sqrt(32)
  for (int idx = tid; idx < SS*SS; idx += 256){
    int qi = idx / SS, ki = idx % SS;
    float a = 0.f;
    #pragma unroll
    for (int d = 0; d < HDD; ++d) a += qs[qi][d]*ks[ki][d];
    scr[qi][ki] = a*scale;
  }
  __syncthreads();
  if (tid < SS){
    float m = -1e30f;
    for (int ki = 0; ki < SS; ++ki) m = fmaxf(m, scr[tid][ki]);
    float Z = 0.f;
    for (int ki = 0; ki < SS; ++ki){ float e2 = expf(scr[tid][ki]-m); scr[tid][ki] = e2; Z += e2; }
    float iz = 1.f/Z;
    for (int ki = 0; ki < SS; ++ki) scr[tid][ki] *= iz;
  }
  __syncthreads();
  for (int idx = tid; idx < SS*HDD; idx += 256){
    int qi = idx / HDD, d = idx % HDD;
    float a = 0.f;
    for (int ki = 0; ki < SS; ++ki) a += scr[qi][ki]*vs[ki][d];
    o[((size_t)(b*SS + qi))*RR + h*HDD + d] = a;
  }
}

// ---------------- K9b: out-proj, 32 tokens/block ----------------
__global__ __launch_bounds__(256) void k_oproj(const float* __restrict__ ain, const float* __restrict__ w,
                        const float* __restrict__ bias, float* __restrict__ out){
  int t0 = blockIdx.x * 32, tid = threadIdx.x;
  int ty = tid >> 6, tx = tid & 63;
  __shared__ float sx[32*RR];        // 32KB
  {
    const float4* src = (const float4*)(ain + (size_t)t0*RR);
    float4* dst = (float4*)sx;
    for (int i = tid; i < 32*RR/4; i += 256) dst[i] = src[i];
  }
  __syncthreads();
  float a[8][4] = {};
  const float* W = w + tx*4;
  #pragma unroll 8
  for (int d = 0; d < RR; ++d){
    float4 wv4 = *(const float4*)(W + (size_t)d*RR);
    #pragma unroll
    for (int i = 0; i < 8; ++i){
      float xv = sx[(ty*8+i)*RR + d];
      a[i][0]+=xv*wv4.x; a[i][1]+=xv*wv4.y; a[i][2]+=xv*wv4.z; a[i][3]+=xv*wv4.w;
    }
  }
  float4 bb = *(const float4*)(bias + tx*4);
  #pragma unroll
  for (int i = 0; i < 8; ++i){
    *(float4*)(out + (size_t)(t0+ty*8+i)*RR + tx*4) =
      make_float4(a[i][0]+bb.x, a[i][1]+bb.y, a[i][2]+bb.z, a[i][3]+bb.w);
  }
}

// ---------------- K10: mean over S + predictor -> logits fp32 ----------------
__global__ void k_final(const float* __restrict__ oproj, const float* __restrict__ pw,
                        const float* __restrict__ pb, float* __restrict__ out){
  int b = blockIdx.x, tid = threadIdx.x;
  __shared__ float om[RR];
  float a = 0.f;
  for (int s = 0; s < SS; ++s) a += oproj[((size_t)(b*SS + s))*RR + tid];
  om[tid] = a * (1.f/SS);
  __syncthreads();
  if (tid < LL){
    float acc = pb[tid];
    for (int h = 0; h < RR; ++h) acc += om[h]*pw[h*LL + tid];
    out[b*LL + tid] = acc;
  }
}

extern "C" void kernel_launch(void* const* d_in, const int* in_sizes, int n_in,
                              void* d_out, int out_size, void* d_ws, size_t ws_size,
                              hipStream_t stream){
  (void)in_sizes; (void)n_in; (void)out_size; (void)ws_size;
  const float* emb      = (const float*)d_in[0];
  const int*   existing = (const int*)d_in[1];
  const float* mt       = (const float*)d_in[2];
  const float* dpe_w0   = (const float*)d_in[3];
  const float* dpe_b0   = (const float*)d_in[4];
  const float* dpe_w1   = (const float*)d_in[5];
  const float* dpe_b1   = (const float*)d_in[6];
  const float* dpe_w2   = (const float*)d_in[7];
  const float* dpe_b2   = (const float*)d_in[8];
  const float* dpe_wo   = (const float*)d_in[9];
  const float* dpe_bo   = (const float*)d_in[10];
  const float* dpe_lng  = (const float*)d_in[11];
  const float* dpe_lnb  = (const float*)d_in[12];
  const float* fus_w1c  = (const float*)d_in[13];
  const float* fus_w1p  = (const float*)d_in[14];
  const float* fus_b1   = (const float*)d_in[15];
  const float* fus_w2   = (const float*)d_in[16];
  const float* fus_b2   = (const float*)d_in[17];
  const float* gate_w1c = (const float*)d_in[18];
  const float* gate_w1p = (const float*)d_in[19];
  const float* gate_b1  = (const float*)d_in[20];
  const float* gate_w2  = (const float*)d_in[21];
  const float* gate_b2  = (const float*)d_in[22];
  const float* exp_lng  = (const float*)d_in[23];
  const float* exp_lnb  = (const float*)d_in[24];
  const float* rtr_w1   = (const float*)d_in[25];
  const float* rtr_b1   = (const float*)d_in[26];
  const float* rtr_w2   = (const float*)d_in[27];
  const float* rtr_b2   = (const float*)d_in[28];
  const float* red_w1   = (const float*)d_in[29];
  const float* red_b1   = (const float*)d_in[30];
  const float* red_w2   = (const float*)d_in[31];
  const float* red_b2   = (const float*)d_in[32];
  const float* red_lng  = (const float*)d_in[33];
  const float* red_lnb  = (const float*)d_in[34];
  const float* qkv_w    = (const float*)d_in[35];
  const float* qkv_b    = (const float*)d_in[36];
  const float* out_w    = (const float*)d_in[37];
  const float* out_b    = (const float*)d_in[38];
  const float* pred_w   = (const float*)d_in[39];
  const float* pred_b   = (const float*)d_in[40];
  float* out = (float*)d_out;

  // workspace layout (floats)
  float* wsf = (float*)d_ws;
  size_t off = 0;
  float* ctx   = wsf + off; off += (size_t)BB*DD;
  float* pos   = wsf + off; off += (size_t)SS*EE*DD;
  float* posF  = wsf + off; off += (size_t)SS*EE*RR;
  float* posG  = wsf + off; off += (size_t)SS*EE*RR;
  float* rtrD  = wsf + off; off += (size_t)SS*RR;
  float* ctxF  = wsf + off; off += (size_t)BB*EE*RR;
  float* ctxG  = wsf + off; off += (size_t)BB*EE*RR;
  float* rtrC  = wsf + off; off += (size_t)BB*RR;
  int*   cnt   = (int*)(wsf + off); off += 64;
  int*   work  = (int*)(wsf + off); off += MAXWORK;
  int*   wtot  = (int*)(wsf + off); off += 64;
  int*   listT = (int*)(wsf + off); off += (size_t)64*TT;
  float* listW = wsf + off; off += (size_t)64*TT*2;
  float* sec   = wsf + off; off += (size_t)TT*DD;   // reused for q,k,v
  float* x1    = wsf + off; off += (size_t)TT*HH2;  // reused for attn out
  float* xr    = wsf + off; off += (size_t)TT*RR;   // reused for oproj out
  float* q = sec;
  float* k = sec + (size_t)TT*RR;
  float* v = sec + (size_t)2*TT*RR;
  float* attnout = x1;
  float* oproj   = xr;   // xr dead after k_qkv

  k_context<<<BB, 256, 0, stream>>>(emb, existing, ctx);
  k_pos    <<<SS*EE, 256, 0, stream>>>(mt, dpe_w0, dpe_b0, dpe_w1, dpe_b1, dpe_w2, dpe_b2,
                                       dpe_wo, dpe_bo, dpe_lng, dpe_lnb, pos);
  k_posFG  <<<SS*EE, 256, 0, stream>>>(pos, fus_w1p, gate_w1p, posF, posG);
  k_rtrD   <<<SS, 256, 0, stream>>>(mt, rtr_w1, rtrD);
  k_ctxFG  <<<(BB/16)*EE, 512, 0, stream>>>(ctx, fus_w1c, gate_w1c, ctxF, ctxG);
  k_rtrC   <<<BB/4, 256, 0, stream>>>(ctx, rtr_w1, rtrC);
  hipMemsetAsync(cnt, 0, 64*sizeof(int), stream);
  k_router <<<TT/4, 256, 0, stream>>>(emb, existing, rtrD, rtrC, rtr_b1, rtr_w2, rtr_b2,
                                      cnt, listT, listW, sec);
  k_sched  <<<1, 64, 0, stream>>>(cnt, work, wtot);
  k_expert <<<MAXWORK, 256, 0, stream>>>(ctx, ctxF, ctxG, posF, posG,
                                         fus_b1, fus_w2, fus_b2,
                                         gate_b1, gate_w2, gate_b2,
                                         exp_lng, exp_lnb, cnt, listT, listW,
                                         work, wtot, sec);
  k_red1   <<<(TT + 23)/24, 384, 0, stream>>>(sec, red_w1, red_b1, x1);
  k_red2   <<<TT/32, 256, 0, stream>>>(x1, red_w2, red_b2, red_lng, red_lnb, xr);
  {
    dim3 g(TT/32, 3);
    k_qkv  <<<g, 256, 0, stream>>>(xr, qkv_w, qkv_b, q, k, v);
  }
  k_attn   <<<BB*NHH, 256, 0, stream>>>(q, k, v, attnout);
  k_oproj  <<<TT/32, 256, 0, stream>>>(attnout, out_w, out_b, oproj);
  k_final  <<<BB, 256, 0, stream>>>(oproj, pred_w, pred_b, out);
}

// Round 7
// 651.295 us; speedup vs baseline: 1.9178x; 1.9178x over previous
//
#include <hip/hip_runtime.h>
#include <hip/hip_bf16.h>
#include <math.h>

// Shapes
#define BB  512
#define SS  23
#define DD  768
#define EE  8
#define NHH 8
#define RR  256
#define HDD 32
#define LL  50
#define HH2 384            // D/2
#define TT  (BB*SS)        // 11776
#define LN_EPS 1e-5f
#define TBE 8              // tokens per expert-pair block
#define MAXWORK 1536       // >= TT/TBE + 56
#define NCTX 4352          // ctxF(2048) | ctxG(2048) | rtrC(256)

typedef short v8s __attribute__((ext_vector_type(8)));
typedef float v4f __attribute__((ext_vector_type(4)));

__device__ __forceinline__ float gelu(float v){
  return 0.5f*v*(1.f + erff(v*0.70710678118654752f));
}
__device__ __forceinline__ unsigned short f2b(float v){
  __hip_bfloat16 h = __float2bfloat16(v);
  return *reinterpret_cast<unsigned short*>(&h);
}

__device__ __forceinline__ float block_sum(float v, float* red, int nw){
  #pragma unroll
  for (int o = 32; o > 0; o >>= 1) v += __shfl_down(v, o, 64);
  int wid = threadIdx.x >> 6;
  __syncthreads();
  if ((threadIdx.x & 63) == 0) red[wid] = v;
  __syncthreads();
  float s = 0.f;
  for (int i = 0; i < nw; ++i) s += red[i];
  return s;
}

// ---------------- K1: masked-mean context [B,D] (+bf16 copy) ----------------
__global__ void k_context(const float* __restrict__ emb, const int* __restrict__ existing,
                          float* __restrict__ ctx, unsigned short* __restrict__ ctxbf){
  int b = blockIdx.x, tid = threadIdx.x;
  float acc0=0.f, acc1=0.f, acc2=0.f;
  int cnt = 0;
  for (int s = 0; s < SS; ++s){
    if (existing[b*SS + s]){
      ++cnt;
      const float* row = emb + ((size_t)(b*SS + s))*DD;
      acc0 += row[tid]; acc1 += row[tid+256]; acc2 += row[tid+512];
    }
  }
  float inv = 1.0f / ((float)cnt + 1e-8f);
  float v0 = acc0*inv, v1 = acc1*inv, v2 = acc2*inv;
  ctx[(size_t)b*DD + tid      ] = v0;
  ctx[(size_t)b*DD + tid + 256] = v1;
  ctx[(size_t)b*DD + tid + 512] = v2;
  ctxbf[(size_t)b*DD + tid      ] = f2b(v0);
  ctxbf[(size_t)b*DD + tid + 256] = f2b(v1);
  ctxbf[(size_t)b*DD + tid + 512] = f2b(v2);
}

// ---------------- K-pack: transpose-cast all GEMM weights to bf16 [N][K] ----------------
// tiles: red_w1 288 | qkv 192 | out_w 64 | fus 1536 | gate 1536 | rtr 192 = 3808
__global__ __launch_bounds__(256) void k_pack(
    const float* __restrict__ red_w1, const float* __restrict__ qkv_w,
    const float* __restrict__ out_w,  const float* __restrict__ fus_w1c,
    const float* __restrict__ gate_w1c, const float* __restrict__ rtr_w1,
    unsigned short* __restrict__ Wr1t, unsigned short* __restrict__ Wqt,
    unsigned short* __restrict__ Wot,  unsigned short* __restrict__ Wct){
  int t = blockIdx.x, tid = threadIdx.x;
  const float* src; unsigned short* dst;
  int Nsrc, stride, tk, tn;
  if (t < 288){ src = red_w1; dst = Wr1t; Nsrc = 384; stride = 768; tk = t % 24; tn = t / 24; }
  else if (t < 480){
    int u = t - 288, m = u >> 6, v2 = u & 63;
    src = qkv_w + (size_t)m*256*256; dst = Wqt + (size_t)m*256*256;
    Nsrc = 256; stride = 256; tk = v2 & 7; tn = v2 >> 3;
  } else if (t < 544){
    int v2 = t - 480;
    src = out_w; dst = Wot; Nsrc = 256; stride = 256; tk = v2 & 7; tn = v2 >> 3;
  } else if (t < 2080){
    int u = t - 544, e = u / 192, v2 = u % 192;
    src = fus_w1c + (size_t)e*DD*RR; dst = Wct + (size_t)(e*256)*768;
    Nsrc = 256; stride = 768; tk = v2 % 24; tn = v2 / 24;
  } else if (t < 3616){
    int u = t - 2080, e = u / 192, v2 = u % 192;
    src = gate_w1c + (size_t)e*DD*RR; dst = Wct + (size_t)(2048 + e*256)*768;
    Nsrc = 256; stride = 768; tk = v2 % 24; tn = v2 / 24;
  } else {
    int u = t - 3616;
    src = rtr_w1 + (size_t)768*256; dst = Wct + (size_t)4096*768;
    Nsrc = 256; stride = 768; tk = u % 24; tn = u / 24;
  }
  __shared__ float lt[32][33];
  int i0 = tid >> 5, j = tid & 31;
  #pragma unroll
  for (int l = 0; l < 4; ++l){
    int i = i0 + l*8;
    lt[i][j] = src[(size_t)(tk*32 + i)*Nsrc + tn*32 + j];
  }
  __syncthreads();
  #pragma unroll
  for (int l = 0; l < 4; ++l){
    int i = i0 + l*8;
    dst[(size_t)(tn*32 + i)*stride + tk*32 + j] = f2b(lt[j][i]);
  }
}

// ---------------- K-gemm: C[M][N] = A[M][K](bf16) @ Bt[N][K](bf16) + bias; epi ----------------
// grid (M/64, N/64), 256 threads. epi: 0=none, 1=+bias, 2=gelu(+bias)
__global__ __launch_bounds__(256) void k_gemm(
    const unsigned short* __restrict__ A, const unsigned short* __restrict__ Bt,
    const float* __restrict__ bias, float* __restrict__ C,
    int M, int N, int K, int epi){
  int m0 = blockIdx.x * 64, n0 = blockIdx.y * 64;
  int tid = threadIdx.x;
  int w = tid >> 6, lane = tid & 63;
  int fm = lane & 15, q = lane >> 4;
  __shared__ unsigned short As[64*72];
  __shared__ unsigned short Bs[64*72];
  v4f acc[4] = {};
  int sr = tid >> 2, scb = (tid & 3) * 16;
  const unsigned short* Aga = A + (size_t)(m0 + sr)*K + scb;
  const unsigned short* Bga = Bt + (size_t)(n0 + sr)*K + scb;
  unsigned short* Asd = As + sr*72 + scb;
  unsigned short* Bsd = Bs + sr*72 + scb;
  for (int k0 = 0; k0 < K; k0 += 64){
    uint4 a0 = *(const uint4*)(Aga + k0);
    uint4 a1 = *(const uint4*)(Aga + k0 + 8);
    uint4 b0 = *(const uint4*)(Bga + k0);
    uint4 b1 = *(const uint4*)(Bga + k0 + 8);
    __syncthreads();
    *(uint4*)Asd = a0; *(uint4*)(Asd + 8) = a1;
    *(uint4*)Bsd = b0; *(uint4*)(Bsd + 8) = b1;
    __syncthreads();
    const unsigned short* ap = As + (w*16 + fm)*72 + q*8;
    const unsigned short* bp = Bs + fm*72 + q*8;
    #pragma unroll
    for (int kk = 0; kk < 2; ++kk){
      v8s af = *(const v8s*)(ap + kk*32);
      #pragma unroll
      for (int j = 0; j < 4; ++j){
        v8s bf = *(const v8s*)(bp + j*16*72 + kk*32);
        acc[j] = __builtin_amdgcn_mfma_f32_16x16x32_bf16(af, bf, acc[j], 0, 0, 0);
      }
    }
  }
  #pragma unroll
  for (int j = 0; j < 4; ++j){
    int n = n0 + j*16 + fm;
    float bv = bias ? bias[n] : 0.f;
    float* Cp = C + (size_t)(m0 + w*16 + q*4)*N + n;
    #pragma unroll
    for (int r = 0; r < 4; ++r){
      float v = acc[j][r] + bv;
      if (epi == 2) v = gelu(v);
      Cp[(size_t)r*N] = v;
    }
  }
}

// ---------------- K2: DPE -> pos [S,E,D] ----------------
__global__ void k_pos(const float* __restrict__ mt,
                      const float* __restrict__ w0, const float* __restrict__ bi0,
                      const float* __restrict__ w1, const float* __restrict__ bi1,
                      const float* __restrict__ w2, const float* __restrict__ bi2,
                      const float* __restrict__ wo, const float* __restrict__ bo,
                      const float* __restrict__ lng, const float* __restrict__ lnb,
                      float* __restrict__ pos){
  int s = blockIdx.x / EE, e = blockIdx.x % EE, tid = threadIdx.x;
  __shared__ float def[DD];
  __shared__ float hA[RR], hB[RR];
  __shared__ float red[8];
  for (int j = tid; j < DD; j += 256) def[j] = mt[s*DD + j];
  __syncthreads();
  float acc = 0.f;
  { const float* W = w0 + (size_t)e*DD*RR;
    for (int d = 0; d < DD; ++d) acc += def[d] * W[(size_t)d*RR + tid]; }
  hA[tid] = fmaxf(acc + bi0[e*RR + tid], 0.f);
  __syncthreads();
  acc = 0.f;
  { const float* W = w1 + (size_t)e*RR*RR;
    for (int kk = 0; kk < RR; ++kk) acc += hA[kk] * W[kk*RR + tid]; }
  hB[tid] = fmaxf(acc + bi1[e*RR + tid], 0.f);
  __syncthreads();
  acc = 0.f;
  { const float* W = w2 + (size_t)e*RR*RR;
    for (int kk = 0; kk < RR; ++kk) acc += hB[kk] * W[kk*RR + tid]; }
  __syncthreads();
  hA[tid] = fmaxf(acc + bi2[e*RR + tid], 0.f);
  __syncthreads();
  float o[3];
  const float* Wo = wo + (size_t)e*RR*DD;
  #pragma unroll
  for (int j = 0; j < 3; ++j){
    int d = tid + j*256;
    float a = 0.f;
    for (int kk = 0; kk < RR; ++kk) a += hA[kk] * Wo[(size_t)kk*DD + d];
    o[j] = a + bo[e*DD + d] + def[d];
  }
  float mean = block_sum(o[0]+o[1]+o[2], red, 4) * (1.f/DD);
  float dv = 0.f;
  #pragma unroll
  for (int j = 0; j < 3; ++j){ float c = o[j]-mean; dv += c*c; }
  float rstd = rsqrtf(block_sum(dv, red, 4) * (1.f/DD) + LN_EPS);
  #pragma unroll
  for (int j = 0; j < 3; ++j){
    int d = tid + j*256;
    pos[((size_t)(s*EE + e))*DD + d] =
      (o[j]-mean)*rstd*lng[e*DD + d] + lnb[e*DD + d];
  }
}

// ---------------- K2b: posF/posG [S,E,R] ----------------
__global__ void k_posFG(const float* __restrict__ pos,
                        const float* __restrict__ fw1p, const float* __restrict__ gw1p,
                        float* __restrict__ posF, float* __restrict__ posG){
  int s = blockIdx.x / EE, e = blockIdx.x % EE, tid = threadIdx.x;
  __shared__ float p[DD];
  for (int j = tid; j < DD; j += 256) p[j] = pos[((size_t)(s*EE + e))*DD + j];
  __syncthreads();
  float aF = 0.f, aG = 0.f;
  const float* WF = fw1p + (size_t)e*DD*RR;
  const float* WG = gw1p + (size_t)e*DD*RR;
  for (int d = 0; d < DD; ++d){
    float pv = p[d];
    aF += pv * WF[(size_t)d*RR + tid];
    aG += pv * WG[(size_t)d*RR + tid];
  }
  posF[(s*EE + e)*RR + tid] = aF;
  posG[(s*EE + e)*RR + tid] = aG;
}

// ---------------- K2c: router default half [S,R] ----------------
__global__ void k_rtrD(const float* __restrict__ mt, const float* __restrict__ rw1,
                       float* __restrict__ rtrD){
  int s = blockIdx.x, tid = threadIdx.x;
  __shared__ float def[DD];
  for (int j = tid; j < DD; j += 256) def[j] = mt[s*DD + j];
  __syncthreads();
  float a = 0.f;
  for (int d = 0; d < DD; ++d) a += def[d] * rw1[(size_t)d*RR + tid];
  rtrD[s*RR + tid] = a;
}

// ---------------- K4: router -> pair buckets; copies existing rows to secbf ----------------
__global__ void k_router(const float* __restrict__ emb, const int* __restrict__ existing,
                         const float* __restrict__ rtrD, const float* __restrict__ ctxFGR,
                         const float* __restrict__ rb1, const float* __restrict__ rw2,
                         const float* __restrict__ rb2,
                         int* __restrict__ cnt, int* __restrict__ listT,
                         float* __restrict__ listW, unsigned short* __restrict__ secbf){
  int wv = threadIdx.x >> 6, lane = threadIdx.x & 63;
  int t = blockIdx.x*4 + wv;
  int b = t / SS, s = t - b*SS;
  if (existing[t]){
    #pragma unroll
    for (int j = 0; j < DD/64; ++j)
      secbf[(size_t)t*DD + lane + j*64] = f2b(emb[(size_t)t*DD + lane + j*64]);
    return;
  }
  const float* rtrC = ctxFGR + (size_t)b*NCTX + 4096;
  float acc[EE] = {};
  #pragma unroll
  for (int j = 0; j < 4; ++j){
    int idx = lane + j*64;
    float hr = fmaxf(rtrD[s*RR + idx] + rtrC[idx] + rb1[idx], 0.f);
    #pragma unroll
    for (int e = 0; e < EE; ++e) acc[e] += hr * rw2[idx*EE + e];
  }
  #pragma unroll
  for (int e = 0; e < EE; ++e)
    #pragma unroll
    for (int o = 32; o > 0; o >>= 1) acc[e] += __shfl_xor(acc[e], o, 64);
  if (lane == 0){
    float sc[EE];
    float m = -1e30f;
    #pragma unroll
    for (int e = 0; e < EE; ++e){ sc[e] = acc[e] + rb2[e]; m = fmaxf(m, sc[e]); }
    float w[EE]; float Z = 0.f;
    #pragma unroll
    for (int e = 0; e < EE; ++e){ w[e] = expf(sc[e]-m); Z += w[e]; }
    int i0 = 0;
    for (int e = 1; e < EE; ++e) if (w[e] > w[i0]) i0 = e;
    int i1 = -1;
    for (int e = 0; e < EE; ++e) if (e != i0 && (i1 < 0 || w[e] > w[i1])) i1 = e;
    float iz = 1.f/Z;
    int p = i0*EE + i1;
    int idx = atomicAdd(&cnt[p], 1);
    size_t g = (size_t)p*TT + idx;
    listT[g] = t;
    listW[g*2]   = w[i0]*iz;
    listW[g*2+1] = w[i1]*iz;
  }
}

// ---------------- K4b: compact (pair,chunk) work list ----------------
__global__ void k_sched(const int* __restrict__ cnt, int* __restrict__ work,
                        int* __restrict__ wtotal){
  int tid = threadIdx.x;          // 64 threads
  __shared__ int chs[64];
  __shared__ int base[64];
  int n = cnt[tid];
  chs[tid] = (n + TBE - 1) / TBE;
  __syncthreads();
  if (tid == 0){
    int acc = 0;
    for (int p = 0; p < 64; ++p){ base[p] = acc; acc += chs[p]; }
    wtotal[0] = acc;
  }
  __syncthreads();
  int b0 = base[tid], ch = chs[tid];
  for (int j = 0; j < ch; ++j) work[b0 + j] = (tid << 16) | j;
}

// ---------------- K5: expert-pair eval, 8 tokens/block -> secbf (missing rows) ----------------
__global__ __launch_bounds__(256) void k_expert(
    const float* __restrict__ ctx, const float* __restrict__ ctxFGR,
    const float* __restrict__ posF, const float* __restrict__ posG,
    const float* __restrict__ fb1, const float* __restrict__ fw2, const float* __restrict__ fb2,
    const float* __restrict__ gb1, const float* __restrict__ gw2, const float* __restrict__ gb2,
    const float* __restrict__ elng, const float* __restrict__ elnb,
    const int* __restrict__ cnt, const int* __restrict__ listT, const float* __restrict__ listW,
    const int* __restrict__ work, const int* __restrict__ wtotal,
    unsigned short* __restrict__ secbf){
  int wi = blockIdx.x;
  if (wi >= wtotal[0]) return;
  int ent = work[wi];
  int p = ent >> 16, chunk = ent & 0xffff;
  int n = cnt[p];
  int e0 = p >> 3, e1 = p & 7;
  int nt = n - chunk*TBE; if (nt > TBE) nt = TBE;
  int tid = threadIdx.x;
  __shared__ float hfs[TBE*RR];     // 8KB
  __shared__ float mixbuf[TBE*DD];  // 24KB
  __shared__ float gates[TBE];
  __shared__ int   tks[TBE], tkb[TBE], tkss[TBE];
  __shared__ float sws[TBE][2];
  if (tid < TBE){
    int ok = tid < nt;
    size_t g = (size_t)p*TT + chunk*TBE + (ok ? tid : 0);
    int t = listT[g];
    tks[tid] = t; tkb[tid] = t/SS; tkss[tid] = t - (t/SS)*SS;
    sws[tid][0] = listW[g*2]; sws[tid][1] = listW[g*2+1];
  }
  __syncthreads();
  float outreg[2][DD/64] = {};
  int wv = tid >> 6, lane = tid & 63;
  for (int xp = 0; xp < 2; ++xp){
    int e = xp ? e1 : e0;
    // stage hf = relu(ctxF + posF + fb1)
    for (int idx2 = tid; idx2 < TBE*RR; idx2 += 256){
      int i = idx2 >> 8, kk = idx2 & 255;
      float v = 0.f;
      if (i < nt){
        int b = tkb[i], s = tkss[i];
        v = fmaxf(ctxFGR[(size_t)b*NCTX + e*256 + kk] + posF[(s*EE+e)*RR + kk]
                  + fb1[e*RR + kk], 0.f);
      }
      hfs[idx2] = v;
    }
    // gates wave-parallel (2 tokens/wave)
    #pragma unroll
    for (int ii = 0; ii < 2; ++ii){
      int it = wv*2 + ii;
      if (it < nt){
        int b = tkb[it], s = tkss[it];
        float g = 0.f;
        #pragma unroll
        for (int j = 0; j < 4; ++j){
          int idx = lane + j*64;
          float hg = fmaxf(ctxFGR[(size_t)b*NCTX + 2048 + e*256 + idx]
                           + posG[(s*EE+e)*RR + idx] + gb1[e*RR + idx], 0.f);
          g += hg * gw2[e*RR + idx];
        }
        #pragma unroll
        for (int o = 32; o > 0; o >>= 1) g += __shfl_xor(g, o, 64);
        if (lane == 0) gates[it] = 1.f/(1.f + expf(-(g + gb2[e])));
      }
    }
    __syncthreads();
    // GEMM: 192 threads x float4 cols, 8 tokens each
    float acc2[8][4] = {};
    if (tid < 192){
      const float* W = fw2 + (size_t)e*RR*DD + tid*4;
      #pragma unroll 4
      for (int kk = 0; kk < RR; ++kk){
        float4 wv4 = *(const float4*)(W + (size_t)kk*DD);
        #pragma unroll
        for (int i = 0; i < 8; ++i){
          float h = hfs[i*RR + kk];
          acc2[i][0]+=h*wv4.x; acc2[i][1]+=h*wv4.y; acc2[i][2]+=h*wv4.z; acc2[i][3]+=h*wv4.w;
        }
      }
      int d = tid*4;
      float4 bb4 = *(const float4*)(fb2 + (size_t)e*DD + d);
      #pragma unroll
      for (int i = 0; i < 8; ++i){
        if (i < nt){
          float g = gates[i]; int b = tkb[i];
          float4 cv = *(const float4*)(ctx + (size_t)b*DD + d);
          mixbuf[i*DD + d    ] = g*(acc2[i][0]+bb4.x) + (1.f-g)*cv.x;
          mixbuf[i*DD + d + 1] = g*(acc2[i][1]+bb4.y) + (1.f-g)*cv.y;
          mixbuf[i*DD + d + 2] = g*(acc2[i][2]+bb4.z) + (1.f-g)*cv.z;
          mixbuf[i*DD + d + 3] = g*(acc2[i][3]+bb4.w) + (1.f-g)*cv.w;
        }
      }
    }
    __syncthreads();
    // LN + weighted accumulate (wave per 2 tokens)
    #pragma unroll
    for (int ii = 0; ii < 2; ++ii){
      int it = wv*2 + ii;
      if (it < nt){
        float sum = 0.f, sq = 0.f;
        #pragma unroll
        for (int j = 0; j < DD/64; ++j){
          float v2 = mixbuf[it*DD + lane + j*64];
          sum += v2; sq += v2*v2;
        }
        #pragma unroll
        for (int o = 32; o > 0; o >>= 1){
          sum += __shfl_xor(sum, o, 64); sq += __shfl_xor(sq, o, 64);
        }
        float mean = sum*(1.f/DD);
        float rstd = rsqrtf(sq*(1.f/DD) - mean*mean + LN_EPS);
        float sw = sws[it][xp];
        #pragma unroll
        for (int j = 0; j < DD/64; ++j){
          int d = lane + j*64;
          float v2 = (mixbuf[it*DD + d]-mean)*rstd*elng[e*DD + d] + elnb[e*DD + d];
          outreg[ii][j] += sw*v2;
        }
      }
    }
    __syncthreads();
  }
  for (int ii = 0; ii < 2; ++ii){
    int it = wv*2 + ii;
    if (it < nt){
      int t = tks[it];
      #pragma unroll
      for (int j = 0; j < DD/64; ++j)
        secbf[(size_t)t*DD + lane + j*64] = f2b(outreg[ii][j]);
    }
  }
}

// ---------------- K7a: xr = LN(gelu(x1 @ red_w2 + b2)) -> bf16, 16 tokens/block ----------------
__global__ __launch_bounds__(256) void k_red2(
    const float* __restrict__ x1, const float* __restrict__ w2, const float* __restrict__ b2v,
    const float* __restrict__ lng, const float* __restrict__ lnb,
    unsigned short* __restrict__ xrbf){
  int t0 = blockIdx.x * 16, tid = threadIdx.x;
  int ty = tid >> 6, tx = tid & 63;
  __shared__ float sx[16*HH2];        // 24KB
  {
    const float4* src = (const float4*)(x1 + (size_t)t0*HH2);
    float4* dst = (float4*)sx;
    for (int i = tid; i < 16*HH2/4; i += 256) dst[i] = src[i];
  }
  __syncthreads();
  float a[4][4] = {};
  const float* W = w2 + tx*4;
  #pragma unroll 8
  for (int d = 0; d < HH2; ++d){
    float4 w = *(const float4*)(W + (size_t)d*RR);
    #pragma unroll
    for (int i = 0; i < 4; ++i){
      float xv = sx[(ty*4+i)*HH2 + d];
      a[i][0]+=xv*w.x; a[i][1]+=xv*w.y; a[i][2]+=xv*w.z; a[i][3]+=xv*w.w;
    }
  }
  float4 bb = *(const float4*)(b2v + tx*4);
  float4 g4 = *(const float4*)(lng + tx*4);
  float4 be4 = *(const float4*)(lnb + tx*4);
  #pragma unroll
  for (int i = 0; i < 4; ++i){
    float v0=gelu(a[i][0]+bb.x), v1=gelu(a[i][1]+bb.y);
    float v2=gelu(a[i][2]+bb.z), v3=gelu(a[i][3]+bb.w);
    float sum = v0+v1+v2+v3;
    float sq  = v0*v0+v1*v1+v2*v2+v3*v3;
    #pragma unroll
    for (int o = 32; o > 0; o >>= 1){ sum += __shfl_xor(sum,o,64); sq += __shfl_xor(sq,o,64); }
    float mean = sum*(1.f/RR);
    float rstd = rsqrtf(sq*(1.f/RR) - mean*mean + LN_EPS);
    float o0 = (v0-mean)*rstd*g4.x + be4.x;
    float o1 = (v1-mean)*rstd*g4.y + be4.y;
    float o2 = (v2-mean)*rstd*g4.z + be4.z;
    float o3 = (v3-mean)*rstd*g4.w + be4.w;
    uint2 pk;
    pk.x = (unsigned)f2b(o0) | ((unsigned)f2b(o1) << 16);
    pk.y = (unsigned)f2b(o2) | ((unsigned)f2b(o3) << 16);
    *(uint2*)(xrbf + (size_t)(t0+ty*4+i)*RR + tx*4) = pk;
  }
}

// ---------------- K9: attention per (b,head); reads qcat [T][768]; writes bf16 ----------------
__global__ void k_attn(const float* __restrict__ qcat, unsigned short* __restrict__ attnbf){
  int bh = blockIdx.x, b = bh / NHH, h = bh % NHH, tid = threadIdx.x;
  __shared__ float qs[SS][HDD], ks[SS][HDD], vs[SS][HDD];
  __shared__ float scr[SS][SS+1];
  for (int idx = tid; idx < SS*HDD; idx += 256){
    int s = idx / HDD, d = idx % HDD;
    size_t g = ((size_t)(b*SS + s))*768 + h*HDD + d;
    qs[s][d] = qcat[g]; ks[s][d] = qcat[g + 256]; vs[s][d] = qcat[g + 512];
  }
  __syncthreads();
  const float scale = 0.17677669529663687f;  // 1/sqrt(32)
  for (int idx = tid; idx < SS*SS; idx += 256){
    int qi = idx / SS, ki = idx % SS;
    float a = 0.f;
    #pragma unroll
    for (int d = 0; d < HDD; ++d) a += qs[qi][d]*ks[ki][d];
    scr[qi][ki] = a*scale;
  }
  __syncthreads();
  if (tid < SS){
    float m = -1e30f;
    for (int ki = 0; ki < SS; ++ki) m = fmaxf(m, scr[tid][ki]);
    float Z = 0.f;
    for (int ki = 0; ki < SS; ++ki){ float e2 = expf(scr[tid][ki]-m); scr[tid][ki] = e2; Z += e2; }
    float iz = 1.f/Z;
    for (int ki = 0; ki < SS; ++ki) scr[tid][ki] *= iz;
  }
  __syncthreads();
  for (int idx = tid; idx < SS*HDD; idx += 256){
    int qi = idx / HDD, d = idx % HDD;
    float a = 0.f;
    for (int ki = 0; ki < SS; ++ki) a += scr[qi][ki]*vs[ki][d];
    attnbf[((size_t)(b*SS + qi))*RR + h*HDD + d] = f2b(a);
  }
}

// ---------------- K10: mean over S + predictor -> logits fp32 ----------------
__global__ void k_final(const float* __restrict__ oproj, const float* __restrict__ pw,
                        const float* __restrict__ pb, float* __restrict__ out){
  int b = blockIdx.x, tid = threadIdx.x;
  __shared__ float om[RR];
  float a = 0.f;
  for (int s = 0; s < SS; ++s) a += oproj[((size_t)(b*SS + s))*RR + tid];
  om[tid] = a * (1.f/SS);
  __syncthreads();
  if (tid < LL){
    float acc = pb[tid];
    for (int h = 0; h < RR; ++h) acc += om[h]*pw[h*LL + tid];
    out[b*LL + tid] = acc;
  }
}

extern "C" void kernel_launch(void* const* d_in, const int* in_sizes, int n_in,
                              void* d_out, int out_size, void* d_ws, size_t ws_size,
                              hipStream_t stream){
  (void)in_sizes; (void)n_in; (void)out_size; (void)ws_size;
  const float* emb      = (const float*)d_in[0];
  const int*   existing = (const int*)d_in[1];
  const float* mt       = (const float*)d_in[2];
  const float* dpe_w0   = (const float*)d_in[3];
  const float* dpe_b0   = (const float*)d_in[4];
  const float* dpe_w1   = (const float*)d_in[5];
  const float* dpe_b1   = (const float*)d_in[6];
  const float* dpe_w2   = (const float*)d_in[7];
  const float* dpe_b2   = (const float*)d_in[8];
  const float* dpe_wo   = (const float*)d_in[9];
  const float* dpe_bo   = (const float*)d_in[10];
  const float* dpe_lng  = (const float*)d_in[11];
  const float* dpe_lnb  = (const float*)d_in[12];
  const float* fus_w1c  = (const float*)d_in[13];
  const float* fus_w1p  = (const float*)d_in[14];
  const float* fus_b1   = (const float*)d_in[15];
  const float* fus_w2   = (const float*)d_in[16];
  const float* fus_b2   = (const float*)d_in[17];
  const float* gate_w1c = (const float*)d_in[18];
  const float* gate_w1p = (const float*)d_in[19];
  const float* gate_b1  = (const float*)d_in[20];
  const float* gate_w2  = (const float*)d_in[21];
  const float* gate_b2  = (const float*)d_in[22];
  const float* exp_lng  = (const float*)d_in[23];
  const float* exp_lnb  = (const float*)d_in[24];
  const float* rtr_w1   = (const float*)d_in[25];
  const float* rtr_b1   = (const float*)d_in[26];
  const float* rtr_w2   = (const float*)d_in[27];
  const float* rtr_b2   = (const float*)d_in[28];
  const float* red_w1   = (const float*)d_in[29];
  const float* red_b1   = (const float*)d_in[30];
  const float* red_w2   = (const float*)d_in[31];
  const float* red_b2   = (const float*)d_in[32];
  const float* red_lng  = (const float*)d_in[33];
  const float* red_lnb  = (const float*)d_in[34];
  const float* qkv_w    = (const float*)d_in[35];
  const float* qkv_b    = (const float*)d_in[36];
  const float* out_w    = (const float*)d_in[37];
  const float* out_b    = (const float*)d_in[38];
  const float* pred_w   = (const float*)d_in[39];
  const float* pred_b   = (const float*)d_in[40];
  float* out = (float*)d_out;

  // workspace layout (float units); aliases noted
  float* wsf = (float*)d_ws;
  size_t off = 0;
  float* ctx    = wsf + off; off += (size_t)BB*DD;
  unsigned short* ctxbf = (unsigned short*)(wsf + off); off += (size_t)BB*DD/2;
  float* pos    = wsf + off; off += (size_t)SS*EE*DD;
  float* posF   = wsf + off; off += (size_t)SS*EE*RR;
  float* posG   = wsf + off; off += (size_t)SS*EE*RR;
  float* rtrD   = wsf + off; off += (size_t)SS*RR;
  float* ctxFGR = wsf + off; off += (size_t)BB*NCTX;
  int*   cnt    = (int*)(wsf + off); off += 64;
  int*   work   = (int*)(wsf + off); off += MAXWORK;
  int*   wtot   = (int*)(wsf + off); off += 64;
  // region A: listT+listW (used through k_expert) ; attnbf aliases it afterwards
  float* regA   = wsf + off; off += (size_t)192*TT;
  int*   listT  = (int*)regA;
  float* listW  = regA + (size_t)64*TT;
  unsigned short* attnbf = (unsigned short*)regA;          // TT*RR ushort <= region
  // region B: secbf (used through gemm red1) ; oprojf aliases it afterwards
  float* regB   = wsf + off; off += (size_t)TT*DD/2;
  unsigned short* secbf = (unsigned short*)regB;
  float* oprojf = regB;                                    // TT*RR floats <= region
  // region C: x1 (red1 out, red2 in) ; qcat aliases (written after x1 dead)
  float* regC   = wsf + off; off += (size_t)TT*DD;
  float* x1     = regC;                                    // TT*HH2 floats
  float* qcat   = regC;                                    // TT*768 floats
  unsigned short* xrbf = (unsigned short*)(wsf + off); off += (size_t)TT*RR/2;
  unsigned short* Wr1t = (unsigned short*)(wsf + off); off += (size_t)768*384/2;
  unsigned short* Wqt  = (unsigned short*)(wsf + off); off += (size_t)768*256/2;
  unsigned short* Wot  = (unsigned short*)(wsf + off); off += (size_t)256*256/2;
  unsigned short* Wct  = (unsigned short*)(wsf + off); off += (size_t)NCTX*768/2;

  k_context<<<BB, 256, 0, stream>>>(emb, existing, ctx, ctxbf);
  k_pack   <<<3808, 256, 0, stream>>>(red_w1, qkv_w, out_w, fus_w1c, gate_w1c, rtr_w1,
                                      Wr1t, Wqt, Wot, Wct);
  k_pos    <<<SS*EE, 256, 0, stream>>>(mt, dpe_w0, dpe_b0, dpe_w1, dpe_b1, dpe_w2, dpe_b2,
                                       dpe_wo, dpe_bo, dpe_lng, dpe_lnb, pos);
  k_posFG  <<<SS*EE, 256, 0, stream>>>(pos, fus_w1p, gate_w1p, posF, posG);
  k_rtrD   <<<SS, 256, 0, stream>>>(mt, rtr_w1, rtrD);
  {
    dim3 g(BB/64, NCTX/64);   // (8, 68)
    k_gemm <<<g, 256, 0, stream>>>(ctxbf, Wct, (const float*)nullptr, ctxFGR,
                                   BB, NCTX, DD, 0);
  }
  hipMemsetAsync(cnt, 0, 64*sizeof(int), stream);
  k_router <<<TT/4, 256, 0, stream>>>(emb, existing, rtrD, ctxFGR, rtr_b1, rtr_w2, rtr_b2,
                                      cnt, listT, listW, secbf);
  k_sched  <<<1, 64, 0, stream>>>(cnt, work, wtot);
  k_expert <<<MAXWORK, 256, 0, stream>>>(ctx, ctxFGR, posF, posG,
                                         fus_b1, fus_w2, fus_b2,
                                         gate_b1, gate_w2, gate_b2,
                                         exp_lng, exp_lnb, cnt, listT, listW,
                                         work, wtot, secbf);
  {
    dim3 g(TT/64, HH2/64);    // (184, 6)
    k_gemm <<<g, 256, 0, stream>>>(secbf, Wr1t, red_b1, x1, TT, HH2, DD, 2);
  }
  k_red2   <<<TT/16, 256, 0, stream>>>(x1, red_w2, red_b2, red_lng, red_lnb, xrbf);
  {
    dim3 g(TT/64, 768/64);    // (184, 12)
    k_gemm <<<g, 256, 0, stream>>>(xrbf, Wqt, qkv_b, qcat, TT, 768, RR, 1);
  }
  k_attn   <<<BB*NHH, 256, 0, stream>>>(qcat, attnbf);
  {
    dim3 g(TT/64, RR/64);     // (184, 4)
    k_gemm <<<g, 256, 0, stream>>>(attnbf, Wot, out_b, oprojf, TT, RR, RR, 1);
  }
  k_final  <<<BB, 256, 0, stream>>>(oprojf, pred_w, pred_b, out);
}